// Round 1
// baseline (520.593 us; speedup 1.0000x reference)
//
#include <hip/hip_runtime.h>

// YOLO loss: S=7, B=2, C=80. preds cell = 90 f32, target cell = 85 f32.
// Output: 4 f32 scalars (coords, obj, noobj, classes), summed over 401408 cells.
//
// v2: block-cooperative coalesced streaming.
//   - per 64-cell chunk: stage targ slab (64x85) to LDS via coalesced float4,
//     stream preds slab (64x90) coalesced into regs; classes loss computed
//     element-wise with obj/t looked up in LDS; box fields (j>=80) scattered
//     to a padded LDS array; one wave finishes IoU/coords/obj/noobj.
//   - replaces per-thread 360B-stride AoS walking (64 cache lines per load
//     instruction, 22% HBM peak) with 1KB/wave coalesced transactions.

#define NPRED 90
#define NTGT  85
#define NCLS  80
#define CHUNK 64
#define TPB   256
#define PBS   11   // pbox leading-dim pad (odd -> conflict-free lane stride)

#define NT4 (CHUNK * NTGT / 4)   // 1360 float4 per targ slab
#define NP4 (CHUNK * NPRED / 4)  // 1440 float4 per preds slab

__device__ __forceinline__ float sgnf(float x) {
    // matches jnp.sign: sign(0) == 0
    return (x > 0.0f) ? 1.0f : ((x < 0.0f) ? -1.0f : 0.0f);
}

__device__ __forceinline__ float iou_vs_target(
    float acx, float acy, float aw, float ah,
    float bx1, float by1, float bx2, float by2, float area_b)
{
    float ax1 = acx - aw * 0.5f, ay1 = acy - ah * 0.5f;
    float ax2 = acx + aw * 0.5f, ay2 = acy + ah * 0.5f;
    float iw = fmaxf(fminf(ax2, bx2) - fmaxf(ax1, bx1), 0.0f);
    float ih = fmaxf(fminf(ay2, by2) - fmaxf(ay1, by1), 0.0f);
    float inter = iw * ih;
    float area_a = (ax2 - ax1) * (ay2 - ay1);
    return inter / (area_a + area_b - inter);
}

__device__ __forceinline__ void proc_elem(float v, int cl, int j,
    const float* __restrict__ t_lds, float* __restrict__ pbox, float& clsl)
{
    if (j < NCLS) {
        float obj = t_lds[cl * NTGT + NCLS];
        float tv  = t_lds[cl * NTGT + j];
        float d = fmaf(v, obj, -tv);
        clsl = fmaf(d, d, clsl);
    } else {
        pbox[cl * PBS + (j - NCLS)] = v;
    }
}

__device__ __forceinline__ void proc_quad(float4 v, int q,
    const float* __restrict__ t_lds, float* __restrict__ pbox, float& clsl)
{
    int f  = 4 * q;            // flat element index within slab, even
    int cl = f / NPRED;        // magic-mul
    int j  = f - cl * NPRED;   // even, <= 88
    proc_elem(v.x, cl, j, t_lds, pbox, clsl); ++j;
    proc_elem(v.y, cl, j, t_lds, pbox, clsl); ++j;
    if (j == NPRED) { j = 0; ++cl; }   // only possible wrap (j0==88)
    proc_elem(v.z, cl, j, t_lds, pbox, clsl); ++j;
    proc_elem(v.w, cl, j, t_lds, pbox, clsl);
}

__global__ __launch_bounds__(TPB) void yolo_loss_kernel(
    const float* __restrict__ preds, const float* __restrict__ targ,
    float* __restrict__ out, int n_cells)
{
    __shared__ __align__(16) float t_lds[CHUNK * NTGT];  // 21760 B
    __shared__ float pbox[CHUNK * PBS];                  // 2816 B
    __shared__ float red[4][4];

    float coords = 0.0f, objl = 0.0f, noobjl = 0.0f, clsl = 0.0f;

    const int tid = threadIdx.x;
    const int n_chunks = n_cells / CHUNK;

    for (int ch = blockIdx.x; ch < n_chunks; ch += gridDim.x) {
        // slab bases: ch*21760B and ch*23040B -> both 16B aligned
        const float4* tg4 = (const float4*)(targ  + (size_t)ch * (CHUNK * NTGT));
        const float4* pr4 = (const float4*)(preds + (size_t)ch * (CHUNK * NPRED));

        // ---- issue ALL global loads up front (one latency exposure) ----
        float4 t0 = tg4[tid];
        float4 t1 = tg4[tid + 256];
        float4 t2 = tg4[tid + 512];
        float4 t3 = tg4[tid + 768];
        float4 t4 = tg4[tid + 1024];
        const bool ht = tid < (NT4 - 1280);  // 80
        float4 t5 = make_float4(0.f, 0.f, 0.f, 0.f);
        if (ht) t5 = tg4[tid + 1280];

        float4 p0 = pr4[tid];
        float4 p1 = pr4[tid + 256];
        float4 p2 = pr4[tid + 512];
        float4 p3 = pr4[tid + 768];
        float4 p4 = pr4[tid + 1024];
        const bool hp = tid < (NP4 - 1280);  // 160
        float4 p5 = make_float4(0.f, 0.f, 0.f, 0.f);
        if (hp) p5 = pr4[tid + 1280];

        __syncthreads();  // previous iteration's box phase done reading LDS

        float4* tl4 = (float4*)t_lds;
        tl4[tid]        = t0;
        tl4[tid + 256]  = t1;
        tl4[tid + 512]  = t2;
        tl4[tid + 768]  = t3;
        tl4[tid + 1024] = t4;
        if (ht) tl4[tid + 1280] = t5;

        __syncthreads();  // t_lds ready

        // ---- classes loss + scatter box preds to LDS ----
        proc_quad(p0, tid,        t_lds, pbox, clsl);
        proc_quad(p1, tid + 256,  t_lds, pbox, clsl);
        proc_quad(p2, tid + 512,  t_lds, pbox, clsl);
        proc_quad(p3, tid + 768,  t_lds, pbox, clsl);
        proc_quad(p4, tid + 1024, t_lds, pbox, clsl);
        if (hp) proc_quad(p5, tid + 1280, t_lds, pbox, clsl);

        __syncthreads();  // pbox ready

        // ---- box losses: one wave, one lane per cell ----
        if (tid < CHUNK) {
            const float* pb = &pbox[tid * PBS];          // p[80..89]
            const float* tc = &t_lds[tid * NTGT + NCLS]; // t[80..84]
            float obj = tc[0];
            float tcx = tc[1], tcy = tc[2], tw = tc[3], th = tc[4];
            float bx1 = tcx - tw * 0.5f, by1 = tcy - th * 0.5f;
            float bx2 = tcx + tw * 0.5f, by2 = tcy + th * 0.5f;
            float area_b = (bx2 - bx1) * (by2 - by1);

            // box1 = p[86..89], box2 = p[81..84]
            float iou1 = iou_vs_target(pb[6], pb[7], pb[8], pb[9],
                                       bx1, by1, bx2, by2, area_b);
            float iou2 = iou_vs_target(pb[1], pb[2], pb[3], pb[4],
                                       bx1, by1, bx2, by2, area_b);
            bool use2 = iou2 > iou1;  // argmax: tie -> box1

            float pcx = obj * (use2 ? pb[1] : pb[6]);
            float pw  = obj * (use2 ? pb[3] : pb[8]);
            float ph  = obj * (use2 ? pb[4] : pb[9]);

            // center loss uses ONLY cx (ref's [..., :-3] on a 4-vector)
            float dc = pcx - tcx;
            float dw = sgnf(pw) * sqrtf(fabsf(pw) + 1e-6f) - sqrtf(tw);
            float dh = sgnf(ph) * sqrtf(fabsf(ph) + 1e-6f) - sqrtf(th);
            coords = fmaf(dc, dc, coords);
            coords = fmaf(dw, dw, coords);
            coords = fmaf(dh, dh, coords);

            float obj_pred = use2 ? pb[0] : pb[5];  // p[80] : p[85]
            float e1 = fmaf(obj, obj_pred, -obj);
            objl = fmaf(e1, e1, objl);
            float e2 = fmaf(1.0f - obj, obj_pred, -obj);
            noobjl = fmaf(e2, e2, noobjl);
        }
        // next iteration's first __syncthreads() guards LDS reuse
    }

    // ---- remainder cells (none when n_cells % 64 == 0): scalar fallback ----
    for (int cell = n_chunks * CHUNK + (int)(blockIdx.x * TPB + tid);
         cell < n_cells; cell += gridDim.x * TPB) {
        const float* p = preds + (size_t)cell * NPRED;
        const float* t = targ  + (size_t)cell * NTGT;
        float obj = t[NCLS];
        float cls = 0.0f;
        for (int k = 0; k < NCLS; ++k) {
            float d = fmaf(p[k], obj, -t[k]);
            cls = fmaf(d, d, cls);
        }
        clsl += cls;
        float tcx = t[81], tcy = t[82], tw = t[83], th = t[84];
        float bx1 = tcx - tw * 0.5f, by1 = tcy - th * 0.5f;
        float bx2 = tcx + tw * 0.5f, by2 = tcy + th * 0.5f;
        float area_b = (bx2 - bx1) * (by2 - by1);
        float iou1 = iou_vs_target(p[86], p[87], p[88], p[89],
                                   bx1, by1, bx2, by2, area_b);
        float iou2 = iou_vs_target(p[81], p[82], p[83], p[84],
                                   bx1, by1, bx2, by2, area_b);
        bool use2 = iou2 > iou1;
        float pcx = obj * (use2 ? p[81] : p[86]);
        float pw  = obj * (use2 ? p[83] : p[88]);
        float ph  = obj * (use2 ? p[84] : p[89]);
        float dc = pcx - tcx;
        float dw = sgnf(pw) * sqrtf(fabsf(pw) + 1e-6f) - sqrtf(tw);
        float dh = sgnf(ph) * sqrtf(fabsf(ph) + 1e-6f) - sqrtf(th);
        coords = fmaf(dc, dc, coords);
        coords = fmaf(dw, dw, coords);
        coords = fmaf(dh, dh, coords);
        float obj_pred = use2 ? p[80] : p[85];
        float e1 = fmaf(obj, obj_pred, -obj);
        objl = fmaf(e1, e1, objl);
        float e2 = fmaf(1.0f - obj, obj_pred, -obj);
        noobjl = fmaf(e2, e2, noobjl);
    }

    // ---- wave reduce (64 lanes) ----
    #pragma unroll
    for (int off = 32; off > 0; off >>= 1) {
        coords += __shfl_down(coords, off);
        objl   += __shfl_down(objl, off);
        noobjl += __shfl_down(noobjl, off);
        clsl   += __shfl_down(clsl, off);
    }

    int wave = threadIdx.x >> 6;
    int lane = threadIdx.x & 63;
    __syncthreads();  // protect red[] vs earlier LDS use? distinct array, but cheap
    if (lane == 0) {
        red[0][wave] = coords;
        red[1][wave] = objl;
        red[2][wave] = noobjl;
        red[3][wave] = clsl;
    }
    __syncthreads();
    if (threadIdx.x == 0) {
        float c = red[0][0] + red[0][1] + red[0][2] + red[0][3];
        float o = red[1][0] + red[1][1] + red[1][2] + red[1][3];
        float n = red[2][0] + red[2][1] + red[2][2] + red[2][3];
        float k = red[3][0] + red[3][1] + red[3][2] + red[3][3];
        atomicAdd(&out[0], 5.0f * c);   // LAMBDA_COORDS on center+dims
        atomicAdd(&out[1], o);
        atomicAdd(&out[2], 0.5f * n);   // LAMBDA_NOOBJ
        atomicAdd(&out[3], k);
    }
}

extern "C" void kernel_launch(void* const* d_in, const int* in_sizes, int n_in,
                              void* d_out, int out_size, void* d_ws, size_t ws_size,
                              hipStream_t stream) {
    const float* preds = (const float*)d_in[0];
    const float* targ  = (const float*)d_in[1];
    float* out = (float*)d_out;

    int n_cells = in_sizes[0] / NPRED;  // 8192*7*7 = 401408
    int n_chunks = n_cells / CHUNK;     // 6272

    // d_out is poisoned to 0xAA before every timed launch -> zero it on-stream.
    hipMemsetAsync(d_out, 0, (size_t)out_size * sizeof(float), stream);

    int blocks = n_chunks > 0 ? n_chunks : 1;
    hipLaunchKernelGGL(yolo_loss_kernel, dim3(blocks), dim3(TPB), 0, stream,
                       preds, targ, out, n_cells);
}

// Round 2
// 297.497 us; speedup vs baseline: 1.7499x; 1.7499x over previous
//
#include <hip/hip_runtime.h>

// YOLO loss: S=7, B=2, C=80. preds cell = 90 f32, target cell = 85 f32.
// Output: 4 f32 scalars (coords, obj, noobj, classes), summed over 401408 cells.
//
// v3: v2's coalesced streaming + NO contended atomics.
//   Evidence (r1 post-mortem): WRITE_SIZE scaled exactly 4x with atomic count
//   (196->784 KB), duration ~ atomic count at ~13-23 ns per same-line RMW,
//   all pipes idle -> both v1 and v2 were bound by serialized same-cacheline
//   device-scope atomicAdds. v3: blocks write partials to d_ws (plain stores),
//   a second 1-block kernel reduces 4x1536 floats and writes scaled outputs.
//   Grid fixed at 1536 = 6 blocks/CU (LDS occupancy limit), grid-stride chunks.

#define NPRED 90
#define NTGT  85
#define NCLS  80
#define CHUNK 64
#define TPB   256
#define PBS   11   // pbox leading-dim pad (odd -> conflict-free lane stride)
#define NBLK  1536 // 6 blocks/CU * 256 CUs (LDS-bound occupancy)

#define NT4 (CHUNK * NTGT / 4)   // 1360 float4 per targ slab
#define NP4 (CHUNK * NPRED / 4)  // 1440 float4 per preds slab

__device__ __forceinline__ float sgnf(float x) {
    // matches jnp.sign: sign(0) == 0
    return (x > 0.0f) ? 1.0f : ((x < 0.0f) ? -1.0f : 0.0f);
}

__device__ __forceinline__ float iou_vs_target(
    float acx, float acy, float aw, float ah,
    float bx1, float by1, float bx2, float by2, float area_b)
{
    float ax1 = acx - aw * 0.5f, ay1 = acy - ah * 0.5f;
    float ax2 = acx + aw * 0.5f, ay2 = acy + ah * 0.5f;
    float iw = fmaxf(fminf(ax2, bx2) - fmaxf(ax1, bx1), 0.0f);
    float ih = fmaxf(fminf(ay2, by2) - fmaxf(ay1, by1), 0.0f);
    float inter = iw * ih;
    float area_a = (ax2 - ax1) * (ay2 - ay1);
    return inter / (area_a + area_b - inter);
}

__device__ __forceinline__ void proc_elem(float v, int cl, int j, float obj,
    const float* __restrict__ t_lds, float* __restrict__ pbox, float& clsl)
{
    if (j < NCLS) {
        float tv = t_lds[cl * NTGT + j];
        float d = fmaf(v, obj, -tv);
        clsl = fmaf(d, d, clsl);
    } else {
        pbox[cl * PBS + (j - NCLS)] = v;
    }
}

__device__ __forceinline__ void proc_quad(float4 v, int q,
    const float* __restrict__ t_lds, float* __restrict__ pbox, float& clsl)
{
    int f  = 4 * q;            // flat element index within slab, even
    int cl = f / NPRED;        // magic-mul
    int j  = f - cl * NPRED;   // even, <= 88
    if (j != 88) {
        // all 4 elements in cell cl
        float obj = t_lds[cl * NTGT + NCLS];   // broadcast across same-cl lanes
        proc_elem(v.x, cl, j,     obj, t_lds, pbox, clsl);
        proc_elem(v.y, cl, j + 1, obj, t_lds, pbox, clsl);
        proc_elem(v.z, cl, j + 2, obj, t_lds, pbox, clsl);
        proc_elem(v.w, cl, j + 3, obj, t_lds, pbox, clsl);
    } else {
        // j=88,89 are box fields of cl; wrap to classes 0,1 of cl+1
        pbox[cl * PBS + 8] = v.x;
        pbox[cl * PBS + 9] = v.y;
        float obj2 = t_lds[(cl + 1) * NTGT + NCLS];
        proc_elem(v.z, cl + 1, 0, obj2, t_lds, pbox, clsl);
        proc_elem(v.w, cl + 1, 1, obj2, t_lds, pbox, clsl);
    }
}

__global__ __launch_bounds__(TPB) void yolo_loss_kernel(
    const float* __restrict__ preds, const float* __restrict__ targ,
    float* __restrict__ part, float* __restrict__ out,
    int n_cells, int mode)
{
    __shared__ __align__(16) float t_lds[CHUNK * NTGT];  // 21760 B
    __shared__ float pbox[CHUNK * PBS];                  // 2816 B
    __shared__ float red[4][4];

    float coords = 0.0f, objl = 0.0f, noobjl = 0.0f, clsl = 0.0f;

    const int tid = threadIdx.x;
    const int n_chunks = n_cells / CHUNK;

    for (int ch = blockIdx.x; ch < n_chunks; ch += gridDim.x) {
        // slab bases: ch*21760B and ch*23040B -> both 16B aligned
        const float4* tg4 = (const float4*)(targ  + (size_t)ch * (CHUNK * NTGT));
        const float4* pr4 = (const float4*)(preds + (size_t)ch * (CHUNK * NPRED));

        // ---- issue ALL global loads up front (one latency exposure) ----
        float4 t0 = tg4[tid];
        float4 t1 = tg4[tid + 256];
        float4 t2 = tg4[tid + 512];
        float4 t3 = tg4[tid + 768];
        float4 t4 = tg4[tid + 1024];
        const bool ht = tid < (NT4 - 1280);  // 80
        float4 t5 = make_float4(0.f, 0.f, 0.f, 0.f);
        if (ht) t5 = tg4[tid + 1280];

        float4 p0 = pr4[tid];
        float4 p1 = pr4[tid + 256];
        float4 p2 = pr4[tid + 512];
        float4 p3 = pr4[tid + 768];
        float4 p4 = pr4[tid + 1024];
        const bool hp = tid < (NP4 - 1280);  // 160
        float4 p5 = make_float4(0.f, 0.f, 0.f, 0.f);
        if (hp) p5 = pr4[tid + 1280];

        __syncthreads();  // previous iteration's box phase done reading LDS

        float4* tl4 = (float4*)t_lds;
        tl4[tid]        = t0;
        tl4[tid + 256]  = t1;
        tl4[tid + 512]  = t2;
        tl4[tid + 768]  = t3;
        tl4[tid + 1024] = t4;
        if (ht) tl4[tid + 1280] = t5;

        __syncthreads();  // t_lds ready

        // ---- classes loss + scatter box preds to LDS ----
        proc_quad(p0, tid,        t_lds, pbox, clsl);
        proc_quad(p1, tid + 256,  t_lds, pbox, clsl);
        proc_quad(p2, tid + 512,  t_lds, pbox, clsl);
        proc_quad(p3, tid + 768,  t_lds, pbox, clsl);
        proc_quad(p4, tid + 1024, t_lds, pbox, clsl);
        if (hp) proc_quad(p5, tid + 1280, t_lds, pbox, clsl);

        __syncthreads();  // pbox ready

        // ---- box losses: one wave, one lane per cell ----
        if (tid < CHUNK) {
            const float* pb = &pbox[tid * PBS];          // p[80..89]
            const float* tc = &t_lds[tid * NTGT + NCLS]; // t[80..84]
            float obj = tc[0];
            float tcx = tc[1], tcy = tc[2], tw = tc[3], th = tc[4];
            float bx1 = tcx - tw * 0.5f, by1 = tcy - th * 0.5f;
            float bx2 = tcx + tw * 0.5f, by2 = tcy + th * 0.5f;
            float area_b = (bx2 - bx1) * (by2 - by1);

            // box1 = p[86..89], box2 = p[81..84]
            float iou1 = iou_vs_target(pb[6], pb[7], pb[8], pb[9],
                                       bx1, by1, bx2, by2, area_b);
            float iou2 = iou_vs_target(pb[1], pb[2], pb[3], pb[4],
                                       bx1, by1, bx2, by2, area_b);
            bool use2 = iou2 > iou1;  // argmax: tie -> box1

            float pcx = obj * (use2 ? pb[1] : pb[6]);
            float pw  = obj * (use2 ? pb[3] : pb[8]);
            float ph  = obj * (use2 ? pb[4] : pb[9]);

            // center loss uses ONLY cx (ref's [..., :-3] on a 4-vector)
            float dc = pcx - tcx;
            float dw = sgnf(pw) * sqrtf(fabsf(pw) + 1e-6f) - sqrtf(tw);
            float dh = sgnf(ph) * sqrtf(fabsf(ph) + 1e-6f) - sqrtf(th);
            coords = fmaf(dc, dc, coords);
            coords = fmaf(dw, dw, coords);
            coords = fmaf(dh, dh, coords);

            float obj_pred = use2 ? pb[0] : pb[5];  // p[80] : p[85]
            float e1 = fmaf(obj, obj_pred, -obj);
            objl = fmaf(e1, e1, objl);
            float e2 = fmaf(1.0f - obj, obj_pred, -obj);
            noobjl = fmaf(e2, e2, noobjl);
        }
        // next iteration's first __syncthreads() guards LDS reuse
    }

    // ---- remainder cells (none when n_cells % 64 == 0): scalar fallback ----
    for (int cell = n_chunks * CHUNK + (int)(blockIdx.x * TPB + tid);
         cell < n_cells; cell += gridDim.x * TPB) {
        const float* p = preds + (size_t)cell * NPRED;
        const float* t = targ  + (size_t)cell * NTGT;
        float obj = t[NCLS];
        float cls = 0.0f;
        for (int k = 0; k < NCLS; ++k) {
            float d = fmaf(p[k], obj, -t[k]);
            cls = fmaf(d, d, cls);
        }
        clsl += cls;
        float tcx = t[81], tcy = t[82], tw = t[83], th = t[84];
        float bx1 = tcx - tw * 0.5f, by1 = tcy - th * 0.5f;
        float bx2 = tcx + tw * 0.5f, by2 = tcy + th * 0.5f;
        float area_b = (bx2 - bx1) * (by2 - by1);
        float iou1 = iou_vs_target(p[86], p[87], p[88], p[89],
                                   bx1, by1, bx2, by2, area_b);
        float iou2 = iou_vs_target(p[81], p[82], p[83], p[84],
                                   bx1, by1, bx2, by2, area_b);
        bool use2 = iou2 > iou1;
        float pcx = obj * (use2 ? p[81] : p[86]);
        float pw  = obj * (use2 ? p[83] : p[88]);
        float ph  = obj * (use2 ? p[84] : p[89]);
        float dc = pcx - tcx;
        float dw = sgnf(pw) * sqrtf(fabsf(pw) + 1e-6f) - sqrtf(tw);
        float dh = sgnf(ph) * sqrtf(fabsf(ph) + 1e-6f) - sqrtf(th);
        coords = fmaf(dc, dc, coords);
        coords = fmaf(dw, dw, coords);
        coords = fmaf(dh, dh, coords);
        float obj_pred = use2 ? p[80] : p[85];
        float e1 = fmaf(obj, obj_pred, -obj);
        objl = fmaf(e1, e1, objl);
        float e2 = fmaf(1.0f - obj, obj_pred, -obj);
        noobjl = fmaf(e2, e2, noobjl);
    }

    // ---- wave reduce (64 lanes) ----
    #pragma unroll
    for (int off = 32; off > 0; off >>= 1) {
        coords += __shfl_down(coords, off);
        objl   += __shfl_down(objl, off);
        noobjl += __shfl_down(noobjl, off);
        clsl   += __shfl_down(clsl, off);
    }

    int wave = threadIdx.x >> 6;
    int lane = threadIdx.x & 63;
    __syncthreads();
    if (lane == 0) {
        red[0][wave] = coords;
        red[1][wave] = objl;
        red[2][wave] = noobjl;
        red[3][wave] = clsl;
    }
    __syncthreads();
    if (threadIdx.x == 0) {
        float c = red[0][0] + red[0][1] + red[0][2] + red[0][3];
        float o = red[1][0] + red[1][1] + red[1][2] + red[1][3];
        float n = red[2][0] + red[2][1] + red[2][2] + red[2][3];
        float k = red[3][0] + red[3][1] + red[3][2] + red[3][3];
        if (mode == 0) {
            // component-major partials: no contention, plain stores
            int nb = gridDim.x;
            part[0 * nb + blockIdx.x] = c;
            part[1 * nb + blockIdx.x] = o;
            part[2 * nb + blockIdx.x] = n;
            part[3 * nb + blockIdx.x] = k;
        } else {
            atomicAdd(&out[0], 5.0f * c);
            atomicAdd(&out[1], o);
            atomicAdd(&out[2], 0.5f * n);
            atomicAdd(&out[3], k);
        }
    }
}

// one block, 4 waves: wave w reduces component w over nblk partials
__global__ __launch_bounds__(256) void yolo_reduce_kernel(
    const float* __restrict__ part, float* __restrict__ out, int nblk)
{
    int w = threadIdx.x >> 6;
    int lane = threadIdx.x & 63;
    float s = 0.0f;
    for (int i = lane; i < nblk; i += 64) s += part[w * nblk + i];
    #pragma unroll
    for (int off = 32; off > 0; off >>= 1) s += __shfl_down(s, off);
    if (lane == 0) {
        float scale = (w == 0) ? 5.0f : (w == 2) ? 0.5f : 1.0f;
        out[w] = s * scale;  // plain store overwrites poison
    }
}

extern "C" void kernel_launch(void* const* d_in, const int* in_sizes, int n_in,
                              void* d_out, int out_size, void* d_ws, size_t ws_size,
                              hipStream_t stream) {
    const float* preds = (const float*)d_in[0];
    const float* targ  = (const float*)d_in[1];
    float* out = (float*)d_out;

    int n_cells = in_sizes[0] / NPRED;  // 8192*7*7 = 401408

    bool use_ws = ws_size >= (size_t)(4 * NBLK) * sizeof(float);

    if (use_ws) {
        float* part = (float*)d_ws;
        hipLaunchKernelGGL(yolo_loss_kernel, dim3(NBLK), dim3(TPB), 0, stream,
                           preds, targ, part, out, n_cells, 0);
        hipLaunchKernelGGL(yolo_reduce_kernel, dim3(1), dim3(256), 0, stream,
                           part, out, NBLK);
        if (out_size > 4) {
            // poison-clear any extra output slots (none expected)
            hipMemsetAsync(out + 4, 0, (size_t)(out_size - 4) * sizeof(float), stream);
        }
    } else {
        // fallback: contended-atomic path (d_out poisoned -> zero first)
        hipMemsetAsync(d_out, 0, (size_t)out_size * sizeof(float), stream);
        hipLaunchKernelGGL(yolo_loss_kernel, dim3(NBLK), dim3(TPB), 0, stream,
                           preds, targ, (float*)nullptr, out, n_cells, 1);
    }
}